// Round 3
// baseline (1707.533 us; speedup 1.0000x reference)
//
#include <hip/hip_runtime.h>
#include <cstdint>

#define HH   512
#define HD2  1024
#define HD3  1536
#define EE   300
#define VV   32000
#define BB   32
#define LLn  64
#define TT   32

typedef unsigned short u16;
typedef __attribute__((ext_vector_type(8))) short short8;
typedef __attribute__((ext_vector_type(4))) float f32x4;

__device__ __forceinline__ float fast_tanh(float x) {
    float e = __expf(2.f * x);
    return 1.f - 2.f / (e + 1.f);
}
__device__ __forceinline__ float fast_sigmoid(float x) {
    float e = __expf(-x);
    return 1.f / (1.f + e);
}
__device__ __forceinline__ u16 f2bf(float x) {   // RNE
    union { float f; unsigned u; } v; v.f = x;
    unsigned r = v.u + 0x7FFFu + ((v.u >> 16) & 1u);
    return (u16)(r >> 16);
}
__device__ __forceinline__ u16 f_hi_trunc(float x) {
    union { float f; unsigned u; } v; v.f = x;
    return (u16)(v.u >> 16);
}
__device__ __forceinline__ u16 f_lo_trunc(float x) {
    union { float f; unsigned u; } v; v.f = x;
    float res = x - __uint_as_float(v.u & 0xFFFF0000u);   // exact
    union { float f; unsigned u; } w; w.f = res;
    return (u16)(w.u >> 16);
}
__device__ __forceinline__ float bf2f(u16 x) {
    union { unsigned u; float f; } v; v.u = ((unsigned)x) << 16;
    return v.f;
}

// ---------------------------------------------------------------------------
// conv_hilo: fp32 -> (bf16 hi, bf16 lo) truncation split, optional row gather
// and zero padding.
// ---------------------------------------------------------------------------
__global__ __launch_bounds__(256) void conv_hilo(
    const float* __restrict__ src, const int* __restrict__ gather,
    int rows_out, int cols_out, int rows_valid, int cols_valid,
    u16* __restrict__ hi, u16* __restrict__ lo)
{
    int idx = blockIdx.x * 256 + threadIdx.x;
    if (idx >= rows_out * cols_out) return;
    int r = idx / cols_out, c = idx - r * cols_out;
    float x = 0.f;
    if (r < rows_valid && c < cols_valid) {
        int sr = gather ? gather[r] : r;
        x = src[(size_t)sr * cols_valid + c];
    }
    hi[idx] = f_hi_trunc(x);
    lo[idx] = f_lo_trunc(x);
}

// ---------------------------------------------------------------------------
// conv_bf16: elementwise fp32 -> bf16 (RNE).
// ---------------------------------------------------------------------------
__global__ __launch_bounds__(256) void conv_bf16(
    const float* __restrict__ src, u16* __restrict__ dst, int n)
{
    int idx = blockIdx.x * 256 + threadIdx.x;
    if (idx < n) dst[idx] = f2bf(src[idx]);
}

// ---------------------------------------------------------------------------
// transpose_conv: src fp32 [K][N] -> dst bf16 [noff+N][dld] transposed.
// HILO: truncation split into dhi/dlo. else: RNE into dhi only.
// grid = (N/64, K/64), block = 256.
// ---------------------------------------------------------------------------
template<bool HILO>
__global__ __launch_bounds__(256) void transpose_conv(
    const float* __restrict__ src, int K, int N, int noff, int dld,
    u16* __restrict__ dhi, u16* __restrict__ dlo)
{
    __shared__ float t[64][65];
    const int nt = blockIdx.x, ktile = blockIdx.y, tid = threadIdx.x;
    const int n0 = nt * 64, k0 = ktile * 64;
#pragma unroll 4
    for (int i = 0; i < 16; i++) {
        int kr = i * 4 + (tid >> 6);
        int nc = tid & 63;
        t[kr][nc] = src[(size_t)(k0 + kr) * N + n0 + nc];
    }
    __syncthreads();
    const int n = tid >> 2, kc = (tid & 3) * 16;
    unsigned wh[8], wl[8];
#pragma unroll
    for (int jj = 0; jj < 8; jj++) {
        float x0 = t[kc + 2 * jj][n], x1 = t[kc + 2 * jj + 1][n];
        if (HILO) {
            wh[jj] = (unsigned)f_hi_trunc(x0) | ((unsigned)f_hi_trunc(x1) << 16);
            wl[jj] = (unsigned)f_lo_trunc(x0) | ((unsigned)f_lo_trunc(x1) << 16);
        } else {
            wh[jj] = (unsigned)f2bf(x0) | ((unsigned)f2bf(x1) << 16);
        }
    }
    u16* dh = dhi + (size_t)(noff + n0 + n) * dld + k0 + kc;
    *(uint4*)(dh)     = (uint4){wh[0], wh[1], wh[2], wh[3]};
    *(uint4*)(dh + 8) = (uint4){wh[4], wh[5], wh[6], wh[7]};
    if (HILO) {
        u16* dl = dlo + (size_t)(noff + n0 + n) * dld + k0 + kc;
        *(uint4*)(dl)     = (uint4){wl[0], wl[1], wl[2], wl[3]};
        *(uint4*)(dl + 8) = (uint4){wl[4], wl[5], wl[6], wl[7]};
    }
}

// ---------------------------------------------------------------------------
// pre_mfma: C[M x N] = A @ W + bias via bf16 hi/lo x3 MFMA. Output fp32 or
// bf16(RNE). Tile 256(M) x 64(N), K staged 32. grid = (N/64, M/256).
// ---------------------------------------------------------------------------
template<int KSTEPS, bool BF16OUT>
__global__ __launch_bounds__(256) void pre_mfma(
    const u16* __restrict__ Ahi, const u16* __restrict__ Alo,
    const u16* __restrict__ Whi, const u16* __restrict__ Wlo,
    const float* __restrict__ bias, void* __restrict__ Cout, int N)
{
    __shared__ u16 ah[256 * 40], al[256 * 40];
    __shared__ u16 bh[64 * 40],  bl[64 * 40];
    const int nb = blockIdx.x, mb = blockIdx.y, tid = threadIdx.x;
    const int w = tid >> 6, ln = tid & 63;
    const int quad = ln >> 4, lm = ln & 15;
    const int n0 = nb * 64;
    const int K = KSTEPS * 32;

    f32x4 acc[4][4];
#pragma unroll
    for (int r = 0; r < 4; r++)
#pragma unroll
        for (int c = 0; c < 4; c++)
            acc[r][c] = (f32x4){0.f, 0.f, 0.f, 0.f};

    for (int kt = 0; kt < KSTEPS; kt++) {
        const int k0 = kt * 32;
        {
            const uint4* sh = (const uint4*)(Ahi + (size_t)(mb * 256 + tid) * K + k0);
            const uint4* sl = (const uint4*)(Alo + (size_t)(mb * 256 + tid) * K + k0);
            uint4 h0 = sh[0], h1 = sh[1], h2 = sh[2], h3 = sh[3];
            uint4 l0 = sl[0], l1 = sl[1], l2 = sl[2], l3 = sl[3];
            uint4* dh = (uint4*)(ah + tid * 40);
            dh[0] = h0; dh[1] = h1; dh[2] = h2; dh[3] = h3;
            uint4* dl = (uint4*)(al + tid * 40);
            dl[0] = l0; dl[1] = l1; dl[2] = l2; dl[3] = l3;
        }
        {
            const int kr = tid >> 3, c8 = (tid & 7) * 8;
            union { uint4 v; u16 u[8]; } uh, ul;
            uh.v = *(const uint4*)(Whi + (size_t)(k0 + kr) * N + n0 + c8);
            ul.v = *(const uint4*)(Wlo + (size_t)(k0 + kr) * N + n0 + c8);
#pragma unroll
            for (int j = 0; j < 8; j++) {
                bh[(c8 + j) * 40 + kr] = uh.u[j];
                bl[(c8 + j) * 40 + kr] = ul.u[j];
            }
        }
        __syncthreads();
        short8 afh[4], afl[4], bfh[4], bfl[4];
#pragma unroll
        for (int r = 0; r < 4; r++) {
            afh[r] = *(const short8*)(ah + ((w * 4 + r) * 16 + lm) * 40 + quad * 8);
            afl[r] = *(const short8*)(al + ((w * 4 + r) * 16 + lm) * 40 + quad * 8);
        }
#pragma unroll
        for (int c = 0; c < 4; c++) {
            bfh[c] = *(const short8*)(bh + (c * 16 + lm) * 40 + quad * 8);
            bfl[c] = *(const short8*)(bl + (c * 16 + lm) * 40 + quad * 8);
        }
#pragma unroll
        for (int r = 0; r < 4; r++)
#pragma unroll
            for (int c = 0; c < 4; c++) {
                acc[r][c] = __builtin_amdgcn_mfma_f32_16x16x32_bf16(
                    afh[r], bfh[c], acc[r][c], 0, 0, 0);
                acc[r][c] = __builtin_amdgcn_mfma_f32_16x16x32_bf16(
                    afh[r], bfl[c], acc[r][c], 0, 0, 0);
                acc[r][c] = __builtin_amdgcn_mfma_f32_16x16x32_bf16(
                    afl[r], bfh[c], acc[r][c], 0, 0, 0);
            }
        __syncthreads();
    }
#pragma unroll
    for (int r = 0; r < 4; r++) {
        int row = mb * 256 + (w * 4 + r) * 16 + quad * 4;
#pragma unroll
        for (int c = 0; c < 4; c++) {
            int col = n0 + c * 16 + lm;
            float bo = bias[col];
#pragma unroll
            for (int q2 = 0; q2 < 4; q2++) {
                float val = acc[r][c][q2] + bo;
                if (BF16OUT)
                    ((u16*)Cout)[(size_t)(row + q2) * N + col] = f2bf(val);
                else
                    ((float*)Cout)[(size_t)(row + q2) * N + col] = val;
            }
        }
    }
}

// ---------------------------------------------------------------------------
// step_a: gates1[32 x 1536] = s_t @ [W_a | W_hzr] via hi/lo bf16 x3 MFMA.
// W1t pre-transposed [n=1536][k=512] hi/lo. s as hi/lo bf16 rows (stride
// bstride). grid = 96 (one 16-col n-frag per 1-wave block), block = 64.
// No LDS, no barriers: direct global->fragment loads (all L2-hot).
// ---------------------------------------------------------------------------
__global__ __launch_bounds__(64) void step_a(
    const u16* __restrict__ shi, const u16* __restrict__ slo, int bstride,
    const u16* __restrict__ W1hi, const u16* __restrict__ W1lo,
    float* __restrict__ gates1)
{
    const int f = blockIdx.x;            // n-frag 0..95
    const int ln = threadIdx.x;
    const int quad = ln >> 4, lm = ln & 15;
    const int n0 = f * 16;

    f32x4 acc0 = (f32x4){0.f, 0.f, 0.f, 0.f};
    f32x4 acc1 = (f32x4){0.f, 0.f, 0.f, 0.f};
    const u16* wh  = W1hi + (size_t)(n0 + lm) * 512 + quad * 8;
    const u16* wl  = W1lo + (size_t)(n0 + lm) * 512 + quad * 8;
    const u16* ah0 = shi + (size_t)lm * bstride + quad * 8;
    const u16* al0 = slo + (size_t)lm * bstride + quad * 8;
    const u16* ah1 = shi + (size_t)(16 + lm) * bstride + quad * 8;
    const u16* al1 = slo + (size_t)(16 + lm) * bstride + quad * 8;

#pragma unroll
    for (int kt = 0; kt < 16; kt++) {
        const int ko = kt * 32;
        short8 bh  = *(const short8*)(wh + ko);
        short8 bl  = *(const short8*)(wl + ko);
        short8 a0h = *(const short8*)(ah0 + ko);
        short8 a0l = *(const short8*)(al0 + ko);
        short8 a1h = *(const short8*)(ah1 + ko);
        short8 a1l = *(const short8*)(al1 + ko);
        acc0 = __builtin_amdgcn_mfma_f32_16x16x32_bf16(a0h, bh, acc0, 0, 0, 0);
        acc0 = __builtin_amdgcn_mfma_f32_16x16x32_bf16(a0h, bl, acc0, 0, 0, 0);
        acc0 = __builtin_amdgcn_mfma_f32_16x16x32_bf16(a0l, bh, acc0, 0, 0, 0);
        acc1 = __builtin_amdgcn_mfma_f32_16x16x32_bf16(a1h, bh, acc1, 0, 0, 0);
        acc1 = __builtin_amdgcn_mfma_f32_16x16x32_bf16(a1h, bl, acc1, 0, 0, 0);
        acc1 = __builtin_amdgcn_mfma_f32_16x16x32_bf16(a1l, bh, acc1, 0, 0, 0);
    }
    const int col = n0 + lm;
#pragma unroll
    for (int r = 0; r < 4; r++) {
        gates1[(size_t)(quad * 4 + r) * HD3 + col]        = acc0[r];
        gates1[(size_t)(16 + quad * 4 + r) * HD3 + col]   = acc1[r];
    }
}

// ---------------------------------------------------------------------------
// step_b: fused attention + gates + (r*s)@W_hs + s-finalize + sseq hi/lo.
// grid = (4 q, 32 b) [q fastest -> sibling blocks share L2], block = 256.
// ---------------------------------------------------------------------------
__global__ __launch_bounds__(256) void step_b(
    const float* __restrict__ gates1, const u16* __restrict__ Uh16,
    const u16* __restrict__ Gc16, const float* __restrict__ Ge,
    const u16* __restrict__ Whs16,
    const float* __restrict__ b_a, const float* __restrict__ v_w,
    const float* __restrict__ v_b, const float* __restrict__ b_hzr,
    const float* __restrict__ b_hs,
    const float* __restrict__ s_prev, float* __restrict__ s_next,
    u16* __restrict__ sseq_hi, u16* __restrict__ sseq_lo, int t)
{
    const int q = blockIdx.x, b = blockIdx.y, tid = threadIdx.x;
    __shared__ float outs_s[HH];
    __shared__ float vw_s[HH];
    __shared__ float red[256];
    __shared__ float attn_s[LLn];
    __shared__ float rs_s[HH];
    __shared__ float zb_s[128], pst_s[128];

    // P0: outs = gates1[b][0..512) + b_a ; stage v_w
    outs_s[tid]       = gates1[(size_t)b * HD3 + tid]       + b_a[tid];
    outs_s[tid + 256] = gates1[(size_t)b * HD3 + tid + 256] + b_a[tid + 256];
    vw_s[tid]       = v_w[tid];
    vw_s[tid + 256] = v_w[tid + 256];
    __syncthreads();

    // P1: scores — wave w handles l = w*16..w*16+15, lanes stride h (coalesced)
    {
        const int lane = tid & 63, w = tid >> 6;
        for (int lt = 0; lt < 16; lt++) {
            const int l = w * 16 + lt;
            const u16* up = Uh16 + ((size_t)(b * LLn + l)) * HH;
            float acc = 0.f;
#pragma unroll
            for (int j = 0; j < 8; j++) {
                int hh = j * 64 + lane;
                acc = fmaf(fast_tanh(outs_s[hh] + bf2f(up[hh])), vw_s[hh], acc);
            }
            for (int o = 32; o > 0; o >>= 1) acc += __shfl_xor(acc, o);
            if (lane == 0) red[l] = acc;
        }
    }
    __syncthreads();

    // P2: softmax over L=64 (wave 0)
    if (tid < 64) {
        float v = red[tid] + v_b[0];
        float m = v;
        for (int o = 32; o > 0; o >>= 1) m = fmaxf(m, __shfl_xor(m, o));
        float e = __expf(v - m);
        float s = e;
        for (int o = 32; o > 0; o >>= 1) s += __shfl_xor(s, o);
        attn_s[tid] = e / s;
    }
    __syncthreads();

    const float* ge = Ge + ((size_t)(b * TT + t)) * HD3;
    const float* sp = s_prev + b * HH;

    // P3a: r-gate + rs for ALL 512 h (needed as gemm2 input)
    {
        const u16* gc = Gc16 + (size_t)b * LLn * HD3 + HH;
        float g1a = 0.f, g1b = 0.f;
#pragma unroll 4
        for (int l = 0; l < LLn; l++) {
            float a = attn_s[l];
            g1a = fmaf(a, bf2f(gc[(size_t)l * HD3 + tid]),       g1a);
            g1b = fmaf(a, bf2f(gc[(size_t)l * HD3 + tid + 256]), g1b);
        }
        float gra = b_hzr[HH + tid]       + ge[HH + tid]
                  + gates1[(size_t)b * HD3 + HD2 + tid]       + g1a;
        float grb = b_hzr[HH + tid + 256] + ge[HH + tid + 256]
                  + gates1[(size_t)b * HD3 + HD2 + tid + 256] + g1b;
        rs_s[tid]       = fast_sigmoid(gra) * sp[tid];
        rs_s[tid + 256] = fast_sigmoid(grb) * sp[tid + 256];
    }
    // P3b: z (waves 0-1) / pst (waves 2-3) for own 128-col slice
    {
        const int c = tid & 127;
        const int hq = q * 128 + c;
        if (tid < 128) {
            const u16* gc = Gc16 + (size_t)b * LLn * HD3;
            float g0 = 0.f;
#pragma unroll 4
            for (int l = 0; l < LLn; l++)
                g0 = fmaf(attn_s[l], bf2f(gc[(size_t)l * HD3 + hq]), g0);
            zb_s[c] = fast_sigmoid(b_hzr[hq] + ge[hq]
                                   + gates1[(size_t)b * HD3 + HH + hq] + g0);
        } else {
            const u16* gc = Gc16 + (size_t)b * LLn * HD3 + HD2;
            float g2 = 0.f;
#pragma unroll 4
            for (int l = 0; l < LLn; l++)
                g2 = fmaf(attn_s[l], bf2f(gc[(size_t)l * HD3 + hq]), g2);
            pst_s[c] = ge[HD2 + hq] + g2 + b_hs[hq];
        }
    }
    __syncthreads();

    // P4: gemm2 slice — col c = q*128+(tid&127), k-half = tid>>7
    {
        const int c = tid & 127, half = tid >> 7;
        const int h0 = q * 128 + c;
        const u16* wp = Whs16 + (size_t)(half * 256) * HH + h0;
        const float* rp = rs_s + half * 256;
        float a0 = 0.f, a1 = 0.f, a2 = 0.f, a3 = 0.f;
#pragma unroll 4
        for (int k = 0; k < 256; k += 4) {
            a0 = fmaf(rp[k + 0], bf2f(wp[(size_t)(k + 0) * HH]), a0);
            a1 = fmaf(rp[k + 1], bf2f(wp[(size_t)(k + 1) * HH]), a1);
            a2 = fmaf(rp[k + 2], bf2f(wp[(size_t)(k + 2) * HH]), a2);
            a3 = fmaf(rp[k + 3], bf2f(wp[(size_t)(k + 3) * HH]), a3);
        }
        red[tid] = (a0 + a1) + (a2 + a3);
    }
    __syncthreads();

    // P5: finalize s, write fp32 + hi/lo bf16 sequence row
    if (tid < 128) {
        const int h0 = q * 128 + tid;
        float st = fast_tanh(pst_s[tid] + red[tid] + red[128 + tid]);
        float sv = sp[h0];
        float sn = fmaf(zb_s[tid], st - sv, sv);
        s_next[(size_t)b * HH + h0] = sn;
        size_t off = ((size_t)b * TT + t) * HH + h0;
        sseq_hi[off] = f_hi_trunc(sn);
        sseq_lo[off] = f_lo_trunc(sn);
    }
}

// ---------------------------------------------------------------------------
// final_gemm: out[1024 x 32000] = s_seq(hi/lo bf16) @ Wt^T + b_out.
// Wt pre-transposed bf16 [n=32000][k=512]. Tile 256(M) x 64(N), K staged 32.
// grid = (4 mb, 500 nb) [mb fastest -> Wt strip L2-shared], block = 256.
// ---------------------------------------------------------------------------
__global__ __launch_bounds__(256) void final_gemm(
    const u16* __restrict__ Ahi, const u16* __restrict__ Alo,
    const u16* __restrict__ Wt, const float* __restrict__ b_out,
    float* __restrict__ out)
{
    __shared__ u16 ah_lds[256 * 40];
    __shared__ u16 al_lds[256 * 40];
    __shared__ u16 b_lds[64 * 40];
    const int mb = blockIdx.x, nb = blockIdx.y, tid = threadIdx.x;
    const int w = tid >> 6, ln = tid & 63;
    const int quad = ln >> 4, lm = ln & 15;
    const int n0 = nb * 64;

    f32x4 acc[4][4];
#pragma unroll
    for (int r = 0; r < 4; r++)
#pragma unroll
        for (int c = 0; c < 4; c++)
            acc[r][c] = (f32x4){0.f, 0.f, 0.f, 0.f};

    for (int kt = 0; kt < 16; kt++) {
        const int k0 = kt * 32;
        {   // stage A hi+lo: row mb*256+tid, 32 u16 each
            const uint4* sh = (const uint4*)(Ahi + (size_t)(mb * 256 + tid) * HH + k0);
            const uint4* sl = (const uint4*)(Alo + (size_t)(mb * 256 + tid) * HH + k0);
            uint4 h0 = sh[0], h1 = sh[1], h2 = sh[2], h3 = sh[3];
            uint4 l0 = sl[0], l1 = sl[1], l2 = sl[2], l3 = sl[3];
            uint4* dh = (uint4*)(ah_lds + tid * 40);
            dh[0] = h0; dh[1] = h1; dh[2] = h2; dh[3] = h3;
            uint4* dl = (uint4*)(al_lds + tid * 40);
            dl[0] = l0; dl[1] = l1; dl[2] = l2; dl[3] = l3;
        }
        {   // stage B: linear copy from pre-transposed Wt (no conversion)
            const int n = tid >> 2, part = tid & 3;
            uint4 v = *(const uint4*)(Wt + (size_t)(n0 + n) * HH + k0 + part * 8);
            *(uint4*)(b_lds + n * 40 + part * 8) = v;
        }
        __syncthreads();
        short8 afh[4], afl[4], bfr[4];
#pragma unroll
        for (int r = 0; r < 4; r++) {
            afh[r] = *(const short8*)(ah_lds + ((w * 4 + r) * 16 + lm) * 40 + quad * 8);
            afl[r] = *(const short8*)(al_lds + ((w * 4 + r) * 16 + lm) * 40 + quad * 8);
        }
#pragma unroll
        for (int c = 0; c < 4; c++)
            bfr[c] = *(const short8*)(b_lds + (c * 16 + lm) * 40 + quad * 8);
#pragma unroll
        for (int r = 0; r < 4; r++)
#pragma unroll
            for (int c = 0; c < 4; c++) {
                acc[r][c] = __builtin_amdgcn_mfma_f32_16x16x32_bf16(
                    afh[r], bfr[c], acc[r][c], 0, 0, 0);
                acc[r][c] = __builtin_amdgcn_mfma_f32_16x16x32_bf16(
                    afl[r], bfr[c], acc[r][c], 0, 0, 0);
            }
        __syncthreads();
    }
#pragma unroll
    for (int r = 0; r < 4; r++) {
        int row = mb * 256 + (w * 4 + r) * 16 + quad * 4;
#pragma unroll
        for (int c = 0; c < 4; c++) {
            int col = n0 + c * 16 + lm;
            float bo = b_out[col];
#pragma unroll
            for (int q = 0; q < 4; q++)
                out[(size_t)(row + q) * VV + col] = acc[r][c][q] + bo;
        }
    }
}

// ---------------------------------------------------------------------------
extern "C" void kernel_launch(void* const* d_in, const int* in_sizes, int n_in,
                              void* d_out, int out_size, void* d_ws, size_t ws_size,
                              hipStream_t stream)
{
    const float* enc_h  = (const float*)d_in[0];
    const float* prev_s = (const float*)d_in[1];
    const int*   tw     = (const int*)  d_in[2];
    const float* embed  = (const float*)d_in[3];
    const float* W_a    = (const float*)d_in[4];
    const float* b_a    = (const float*)d_in[5];
    const float* U_a    = (const float*)d_in[6];
    const float* b_Ua   = (const float*)d_in[7];
    const float* v_w    = (const float*)d_in[8];
    const float* v_b    = (const float*)d_in[9];
    const float* W_emb  = (const float*)d_in[10];
    const float* b_emb  = (const float*)d_in[11];
    const float* W_hzr  = (const float*)d_in[12];
    const float* b_hzr  = (const float*)d_in[13];
    const float* W_hs   = (const float*)d_in[14];
    const float* b_hs   = (const float*)d_in[15];
    const float* W_ctx  = (const float*)d_in[16];
    const float* b_ctx  = (const float*)d_in[17];
    const float* W_out  = (const float*)d_in[18];
    const float* b_out  = (const float*)d_in[19];
    float* out = (float*)d_out;

    float* ws = (float*)d_ws;
    float* Ge     = ws;  ws += 1024 * 1536;    // fp32
    float* gates1 = ws;  ws += 32 * 1536;      // s@[W_a|W_hzr] full-K
    float* s0     = ws;  ws += 32 * 512;
    float* s1     = ws;  ws += 32 * 512;
    u16* Uh16 = (u16*)ws;  ws += (2048 * 512) / 2;
    u16* Gc16 = (u16*)ws;  ws += (2048 * 1536) / 2;
    u16* sqh  = (u16*)ws;  ws += (1024 * 512) / 2;   // s_seq hi
    u16* sql  = (u16*)ws;  ws += (1024 * 512) / 2;   // s_seq lo
    u16* p0hi = (u16*)ws;  ws += (32 * 512) / 2;     // prev_s hi/lo (t=0)
    u16* p0lo = (u16*)ws;  ws += (32 * 512) / 2;
    u16* EHhi = (u16*)ws;  ws += (2048 * 1024) / 2;
    u16* EHlo = (u16*)ws;  ws += (2048 * 1024) / 2;
    u16* UAhi = (u16*)ws;  ws += (1024 * 512) / 2;
    u16* UAlo = (u16*)ws;  ws += (1024 * 512) / 2;
    u16* WChi = (u16*)ws;  ws += (1024 * 1536) / 2;
    u16* WClo = (u16*)ws;  ws += (1024 * 1536) / 2;
    u16* WEhi = (u16*)ws;  ws += (320 * 1536) / 2;
    u16* WElo = (u16*)ws;  ws += (320 * 1536) / 2;
    u16* AGhi = (u16*)ws;  ws += (1024 * 320) / 2;
    u16* AGlo = (u16*)ws;  ws += (1024 * 320) / 2;
    u16* W1hi = (u16*)ws;  ws += (1536 * 512) / 2;   // [W_a|W_hzr]^T hi
    u16* W1lo = (u16*)ws;  ws += (1536 * 512) / 2;
    u16* Wt   = (u16*)ws;  ws += (32000 * 512) / 2;  // W_out^T bf16
    u16* Whs16= (u16*)ws;  ws += (512 * 512) / 2;

    // hi/lo + bf16 conversions
    conv_hilo<<<dim3(64),   256, 0, stream>>>(prev_s, nullptr, 32, 512, 32, 512, p0hi, p0lo);
    conv_hilo<<<dim3(8192), 256, 0, stream>>>(enc_h, nullptr, 2048, 1024, 2048, 1024, EHhi, EHlo);
    conv_hilo<<<dim3(2048), 256, 0, stream>>>(U_a,   nullptr, 1024, 512,  1024, 512,  UAhi, UAlo);
    conv_hilo<<<dim3(6144), 256, 0, stream>>>(W_ctx, nullptr, 1024, 1536, 1024, 1536, WChi, WClo);
    conv_hilo<<<dim3(1920), 256, 0, stream>>>(W_emb, nullptr, 320,  1536, 300,  1536, WEhi, WElo);
    conv_hilo<<<dim3(1280), 256, 0, stream>>>(embed, tw,      1024, 320,  1024, 300,  AGhi, AGlo);
    conv_bf16<<<dim3(1024), 256, 0, stream>>>(W_hs, Whs16, 512 * 512);
    transpose_conv<true><<<dim3(8, 8),   256, 0, stream>>>(W_a,   512, 512,   0,   512, W1hi, W1lo);
    transpose_conv<true><<<dim3(16, 8),  256, 0, stream>>>(W_hzr, 512, 1024,  512, 512, W1hi, W1lo);
    transpose_conv<false><<<dim3(500, 8),256, 0, stream>>>(W_out, 512, 32000, 0,   512, Wt, nullptr);

    // Loop-invariant precomputes via bf16x3 MFMA
    pre_mfma<32, true ><<<dim3(8, 8),  256, 0, stream>>>(EHhi, EHlo, UAhi, UAlo, b_Ua,  Uh16, 512);
    pre_mfma<32, true ><<<dim3(24, 8), 256, 0, stream>>>(EHhi, EHlo, WChi, WClo, b_ctx, Gc16, 1536);
    pre_mfma<10, false><<<dim3(24, 4), 256, 0, stream>>>(AGhi, AGlo, WEhi, WElo, b_emb, Ge,   1536);

    for (int t = 0; t < TT; t++) {
        const u16* shi; const u16* slo; int bstride;
        if (t == 0) { shi = p0hi; slo = p0lo; bstride = 512; }
        else        { shi = sqh + (size_t)(t - 1) * 512;
                      slo = sql + (size_t)(t - 1) * 512; bstride = TT * 512; }
        const float* s_in = (t == 0) ? prev_s : ((t & 1) ? s0 : s1);
        float* s_out = (t & 1) ? s1 : s0;
        step_a<<<dim3(96), 64, 0, stream>>>(shi, slo, bstride, W1hi, W1lo, gates1);
        step_b<<<dim3(4, 32), 256, 0, stream>>>(gates1, Uh16, Gc16, Ge, Whs16,
                                                b_a, v_w, v_b, b_hzr, b_hs,
                                                s_in, s_out, sqh, sql, t);
    }
    final_gemm<<<dim3(4, 500), 256, 0, stream>>>(sqh, sql, Wt, b_out, out);
}